// Round 5
// baseline (226.074 us; speedup 1.0000x reference)
//
#include <hip/hip_runtime.h>

// ---------- common helpers ----------
typedef __attribute__((ext_vector_type(8))) unsigned short ushort8v;
typedef __attribute__((ext_vector_type(8))) __bf16 bf16x8;
typedef __attribute__((ext_vector_type(4))) float floatx4;

__device__ __forceinline__ unsigned short f2b(float f) {
    unsigned u = __float_as_uint(f);
    unsigned r = u + 0x7fffu + ((u >> 16) & 1u);   // RNE
    return (unsigned short)(r >> 16);
}
__device__ __forceinline__ float b2f(unsigned short h) {
    return __uint_as_float(((unsigned)h) << 16);
}

// ============================================================================
// Fragment-swizzled global layout: tensor [T16][KC][16][8] bf16, where
//   elem (t16, kc, l, e) = Mat[t16*16 + l][kc*8 + e]   (row x K, row-major src)
// An MFMA 16x16x32 fragment for k0=kc0*8: lane(quad,l16) reads 16B at
//   ((t16*KC + kc0 + quad)*16 + l16)*16 bytes  -> 64 lanes = 1KB CONTIGUOUS.
// GEMM reads fragments directly global->VGPR: no LDS, no barriers.
// ============================================================================

// ---------- fused prep ----------
// blocks [0,512):        x (8192x2048 f32) -> A2x swizzled bf16 (KC=256)
// blocks [512,2560):     W (2048x1023 f32) -> B2w swizzled bf16 (n-major, KC=256)
// blocks [2560,3584):    softmax(leaf_dist) -> B2p swizzled bf16 (c-major, KC=128), c>=1000 zero
__global__ __launch_bounds__(256) void prep_kernel(const float* __restrict__ x,
                                                   unsigned short* __restrict__ A2x,
                                                   const float* __restrict__ W,
                                                   unsigned short* __restrict__ B2w,
                                                   const float* __restrict__ ld_,
                                                   unsigned short* __restrict__ B2p) {
    __shared__ float tile[32 * 33];
    __shared__ float buf[1000];
    __shared__ float red[8];
    const int b = blockIdx.x, t = threadIdx.x;
    if (b < 512) {                         // ---- cvt+swizzle x: one 16-row slab ----
        const int mt = b;
        const int wave = t >> 6, kco = (t >> 4) & 3, l16 = t & 15;
        const float* xr0 = x + (size_t)(mt * 16 + l16) * 2048;
#pragma unroll 4
        for (int i = 0; i < 16; i++) {
            const int kc = wave * 64 + i * 4 + kco;
            const float* xr = xr0 + kc * 8;
            float4 v0 = *(const float4*)xr;
            float4 v1 = *(const float4*)(xr + 4);
            ushort8v o;
            o[0] = f2b(v0.x); o[1] = f2b(v0.y); o[2] = f2b(v0.z); o[3] = f2b(v0.w);
            o[4] = f2b(v1.x); o[5] = f2b(v1.y); o[6] = f2b(v1.z); o[7] = f2b(v1.w);
            *(ushort8v*)(A2x + ((size_t)(mt * 256 + kc) * 16 + l16) * 8) = o;
        }
    } else if (b < 2560) {                 // ---- transpose+swizzle W ----
        const int idx = b - 512;
        const int n0 = (idx & 31) * 32, k0 = (idx >> 5) * 32;
        const int tx = t & 31, ty = t >> 5;
#pragma unroll
        for (int i = 0; i < 4; i++) {
            int k = k0 + ty + i * 8, n = n0 + tx;
            tile[(ty + i * 8) * 33 + tx] = (n < 1023) ? W[(size_t)k * 1023 + n] : 0.f;
        }
        __syncthreads();
#pragma unroll
        for (int i = 0; i < 4; i++) {
            int n = n0 + ty + i * 8, k = k0 + tx;
            size_t off = ((size_t)((n >> 4) * 256 + (k >> 3)) * 16 + (n & 15)) * 8 + (k & 7);
            B2w[off] = f2b(tile[tx * 33 + ty + i * 8]);
        }
    } else {                               // ---- softmax -> B2p swizzled (+zero pad) ----
        const int l0 = b - 2560;
        const float* r = ld_ + (size_t)l0 * 1000;
        float mx = -3.4e38f;
        for (int i = t; i < 1000; i += 256) { float v = r[i]; buf[i] = v; mx = fmaxf(mx, v); }
#pragma unroll
        for (int o = 32; o > 0; o >>= 1) mx = fmaxf(mx, __shfl_down(mx, o));
        if ((t & 63) == 0) red[t >> 6] = mx;
        __syncthreads();
        mx = fmaxf(fmaxf(red[0], red[1]), fmaxf(red[2], red[3]));
        float s = 0.f;
        for (int i = t; i < 1000; i += 256) { float e = __expf(buf[i] - mx); buf[i] = e; s += e; }
#pragma unroll
        for (int o = 32; o > 0; o >>= 1) s += __shfl_down(s, o);
        if ((t & 63) == 0) red[4 + (t >> 6)] = s;
        __syncthreads();
        float inv = 1.f / (red[4] + red[5] + red[6] + red[7]);
        for (int i = t; i < 1024; i += 256) {
            float pv = (i < 1000) ? buf[i] * inv : 0.f;
            size_t off = ((size_t)((i >> 4) * 128 + (l0 >> 3)) * 16 + (i & 15)) * 8 + (l0 & 7);
            B2p[off] = f2b(pv);
        }
    }
}

// ---------- pp: literal reference recurrence; reads dec row-major, writes A2p swizzled ----------
__global__ __launch_bounds__(256) void pp_kernel(const unsigned short* __restrict__ dec,
                                                 unsigned short* __restrict__ A2p) {
    __shared__ float d[1024];
    __shared__ float pa[1024], pb[1024];
    const int t = threadIdx.x;
    const int rrow = blockIdx.x;
    const unsigned short* row = dec + (size_t)rrow * 1024;
    for (int i = t; i < 1024; i += 256) d[i] = (i < 1023) ? b2f(row[i]) : 0.f;
    if (t == 0) pa[0] = 1.f;
    __syncthreads();
    float* cur = pa; float* nxt = pb;
    for (int dep = 0; dep < 10; dep++) {
        const int half = 1 << dep;
        const int len = half << 1;
        for (int j = t; j < len; j += 256) {
            int tt = j >> dep;
            int s  = j & (half - 1);
            int i2 = 2 * s + tt;
            int u  = i2 >> dep;
            int rr = i2 & (half - 1);
            float dv = d[half - 1 + rr];
            nxt[j] = cur[rr] * (u ? (1.f - dv) : dv);
        }
        __syncthreads();
        float* tmp = cur; cur = nxt; nxt = tmp;
    }
    const int mtb = (rrow >> 4) * 128;     // KC=128 for A2p
    const int li  = (rrow & 15) * 8;
    for (int i = t; i < 1024; i += 256) {
        size_t off = ((size_t)(mtb + (i >> 3)) * 16) * 8 + li + (i & 7);
        A2p[off] = f2b(cur[i]);
    }
}

// ---------- LDS-free fragment-direct bf16 GEMM ----------
// A2 [M/16][KC][16][8], B2 [N/16][KC][16][8], both fragment-swizzled.
// Block 256 thr = 4 waves; BM=64 (4 mt), BN=128 (8 nt); wave tile 32x64.
// Per iter (BK=32): 2 A-frag + 4 B-frag coalesced 1KB loads -> 8 MFMA.
// No LDS, no barriers: waves free-run, compiler pipelines vmcnt.
// XCD swizzle: xcd g owns bm-tiles [16g,16g+16) for all 8 bn.
// EPI 0: sigmoid(acc+bias[col]) -> bf16 row-major ld=1024. EPI 1: f32, col<1000.
template <int EPI>
__global__ __launch_bounds__(256, 4) void gemm_frag(const unsigned short* __restrict__ A2,
                                                    const unsigned short* __restrict__ B2,
                                                    const float* __restrict__ bias,
                                                    unsigned short* __restrict__ obf,
                                                    float* __restrict__ of32,
                                                    int KC, int ldo) {
    const int tid  = threadIdx.x;
    const int lane = tid & 63;
    const int wave = tid >> 6;
    const int wr = wave >> 1, wc = wave & 1;
    const int quad = lane >> 4, l16 = lane & 15;

    const int l   = blockIdx.x;
    const int xcd = l & 7;
    const int j   = l >> 3;                    // 0..127
    const int bmt = xcd * 16 + (j & 15);       // bm tile (64 rows) 0..127
    const int bnt = j >> 4;                    // bn tile (128 cols) 0..7

    const int mt0 = bmt * 4 + wr * 2;          // wave rows: 2 mt slabs
    const int nt0 = bnt * 8 + wc * 4;          // wave cols: 4 nt slabs

    const int lofs = (quad * 16 + l16) * 8;    // fragment lane offset (elements)
    const unsigned short* a0 = A2 + (size_t)(mt0 + 0) * KC * 128 + lofs;
    const unsigned short* a1 = A2 + (size_t)(mt0 + 1) * KC * 128 + lofs;
    const unsigned short* b0 = B2 + (size_t)(nt0 + 0) * KC * 128 + lofs;
    const unsigned short* b1 = B2 + (size_t)(nt0 + 1) * KC * 128 + lofs;
    const unsigned short* b2 = B2 + (size_t)(nt0 + 2) * KC * 128 + lofs;
    const unsigned short* b3 = B2 + (size_t)(nt0 + 3) * KC * 128 + lofs;

    floatx4 acc[2][4] = {};
    const int NIT = KC >> 2;                   // BK=32 -> 4 kchunks/iter

#pragma unroll 2
    for (int it = 0; it < NIT; it++) {
        const size_t ko = (size_t)it * 512;    // 4 kchunks * 128 elems
        bf16x8 af0 = __builtin_bit_cast(bf16x8, *(const ushort8v*)(a0 + ko));
        bf16x8 af1 = __builtin_bit_cast(bf16x8, *(const ushort8v*)(a1 + ko));
        bf16x8 bf0 = __builtin_bit_cast(bf16x8, *(const ushort8v*)(b0 + ko));
        bf16x8 bf1 = __builtin_bit_cast(bf16x8, *(const ushort8v*)(b1 + ko));
        bf16x8 bf2 = __builtin_bit_cast(bf16x8, *(const ushort8v*)(b2 + ko));
        bf16x8 bf3 = __builtin_bit_cast(bf16x8, *(const ushort8v*)(b3 + ko));
        acc[0][0] = __builtin_amdgcn_mfma_f32_16x16x32_bf16(af0, bf0, acc[0][0], 0, 0, 0);
        acc[0][1] = __builtin_amdgcn_mfma_f32_16x16x32_bf16(af0, bf1, acc[0][1], 0, 0, 0);
        acc[0][2] = __builtin_amdgcn_mfma_f32_16x16x32_bf16(af0, bf2, acc[0][2], 0, 0, 0);
        acc[0][3] = __builtin_amdgcn_mfma_f32_16x16x32_bf16(af0, bf3, acc[0][3], 0, 0, 0);
        acc[1][0] = __builtin_amdgcn_mfma_f32_16x16x32_bf16(af1, bf0, acc[1][0], 0, 0, 0);
        acc[1][1] = __builtin_amdgcn_mfma_f32_16x16x32_bf16(af1, bf1, acc[1][1], 0, 0, 0);
        acc[1][2] = __builtin_amdgcn_mfma_f32_16x16x32_bf16(af1, bf2, acc[1][2], 0, 0, 0);
        acc[1][3] = __builtin_amdgcn_mfma_f32_16x16x32_bf16(af1, bf3, acc[1][3], 0, 0, 0);
    }

#pragma unroll
    for (int ni = 0; ni < 4; ni++) {
        const int col = (nt0 + ni) * 16 + l16;
        float bb = 0.f;
        if constexpr (EPI == 0) bb = (col < 1023) ? bias[col] : 0.f;
#pragma unroll
        for (int mi = 0; mi < 2; mi++) {
            const int row0 = (mt0 + mi) * 16 + quad * 4;
#pragma unroll
            for (int r = 0; r < 4; r++) {
                float v = acc[mi][ni][r];
                if constexpr (EPI == 0) {
                    float sgm = 1.f / (1.f + __expf(-(v + bb)));
                    obf[(size_t)(row0 + r) * ldo + col] = f2b(sgm);
                } else {
                    if (col < 1000) of32[(size_t)(row0 + r) * ldo + col] = v;
                }
            }
        }
    }
}

// ---------- host ----------
extern "C" void kernel_launch(void* const* d_in, const int* in_sizes, int n_in,
                              void* d_out, int out_size, void* d_ws, size_t ws_size,
                              hipStream_t stream) {
    const float* x   = (const float*)d_in[0];   // 8192x2048
    const float* W   = (const float*)d_in[1];   // 2048x1023
    const float* b   = (const float*)d_in[2];   // 1023
    const float* ldd = (const float*)d_in[3];   // 1024x1000
    float* out = (float*)d_out;                 // 8192x1000

    char* ws = (char*)d_ws;
    unsigned short* A2x = (unsigned short*)(ws);              // 33,554,432 B (swizzled x bf16)
    unsigned short* A2p = (unsigned short*)(ws);              // overlay: pp output (A2x dead by then)
    unsigned short* B2w = (unsigned short*)(ws + 33554432);   // 4,194,304 B (swizzled W^T)
    unsigned short* dec = (unsigned short*)(ws + 37748736);   // 16,777,216 B (row-major decisions)
    unsigned short* B2p = (unsigned short*)(ws + 54525952);   // 2,097,152 B (swizzled P^T)

    // prep: x-swizzle | W-transpose-swizzle | softmax->swizzle (independent)
    prep_kernel<<<3584, 256, 0, stream>>>(x, A2x, W, B2w, ldd, B2p);
    // decisions = sigmoid(x@W + b), row-major bf16 (cols padded to 1024)
    gemm_frag<0><<<1024, 256, 0, stream>>>(A2x, B2w, b, dec, nullptr, 256, 1024);
    // pp (reference-literal order), writes swizzled A2p
    pp_kernel<<<8192, 256, 0, stream>>>(dec, A2p);
    // out = pp @ P
    gemm_frag<1><<<1024, 256, 0, stream>>>(A2p, B2p, nullptr, nullptr, out, 128, 1000);
}